// Round 1
// baseline (13394.423 us; speedup 1.0000x reference)
//
#include <hip/hip_runtime.h>

typedef __attribute__((ext_vector_type(8))) short bh8;
typedef __attribute__((ext_vector_type(4))) float f32x4;

#define BATCH 16
#define SEQ 2048
#define M_ROWS (BATCH * SEQ)   // 32768
#define KDIM 1024

__device__ __forceinline__ unsigned short f2bf(float f) {
  unsigned u = __float_as_uint(f);
  u = (u + 0x7FFFu + ((u >> 16) & 1u)) >> 16;   // round-to-nearest-even
  return (unsigned short)u;
}
__device__ __forceinline__ float bf2f(unsigned short h) {
  return __uint_as_float(((unsigned)h) << 16);
}

__device__ __forceinline__ f32x4 mfma_bf16(bh8 a, bh8 b, f32x4 c) {
  return __builtin_amdgcn_mfma_f32_16x16x32_bf16(a, b, c, 0, 0, 0);
}

__device__ __forceinline__ void gl2lds16(const void* g, void* l) {
  __builtin_amdgcn_global_load_lds(
      (const __attribute__((address_space(1))) void*)g,
      (__attribute__((address_space(3))) void*)l, 16, 0, 0);
}

__global__ void cvt_bf16_kernel(const float* __restrict__ in,
                                unsigned short* __restrict__ out, int n4) {
  int i = blockIdx.x * blockDim.x + threadIdx.x;
  if (i >= n4) return;
  float4 v = ((const float4*)in)[i];
  ushort4 o;
  o.x = f2bf(v.x); o.y = f2bf(v.y); o.z = f2bf(v.z); o.w = f2bf(v.w);
  ((ushort4*)out)[i] = o;
}

__global__ void fill_ones_kernel(float* __restrict__ p, int n) {
  int i = blockIdx.x * blockDim.x + threadIdx.x;
  if (i < n) p[i] = 1.0f;
}

// C[M,N] = A[M,K] * B[N,K]^T   (A,B bf16 row-major, K = 1024)
// m97-style: 128x128 block tile, 4 waves (2x2), 4x4 16x16x32 MFMA per wave,
// BK=32, global_load_lds width-16 staging, single-buffered LDS.
template<bool BF16OUT>
__global__ __launch_bounds__(256, 2) void gemm_nt(
    const unsigned short* __restrict__ A,
    const unsigned short* __restrict__ Bm,
    void* __restrict__ Cout,
    const float* __restrict__ bias,
    int N)
{
  __shared__ unsigned short As[128 * 32];
  __shared__ unsigned short Bs[128 * 32];
  const int tid = threadIdx.x;
  const int wave = tid >> 6, lane = tid & 63;
  const long tileM = (long)blockIdx.y * 128;
  const long tileN = (long)blockIdx.x * 128;

  // staging map: per round, wave w covers rows [16w,16w+16), lane -> (row=lane>>2, chunk=lane&3)
  const int srow = wave * 16 + (lane >> 2);
  const int scol = (lane & 3) * 8;
  const unsigned short* ga = A + (tileM + srow) * KDIM + scol;
  const unsigned short* gb = Bm + (tileN + srow) * KDIM + scol;
  unsigned short* la = As + wave * 512;   // lds dest = base + lane*16B (HW layout)
  unsigned short* lb = Bs + wave * 512;

  f32x4 acc[4][4];
  #pragma unroll
  for (int i = 0; i < 4; ++i)
    #pragma unroll
    for (int j = 0; j < 4; ++j)
      acc[i][j] = (f32x4){0.f, 0.f, 0.f, 0.f};

  const int wm = wave >> 1, wn = wave & 1;
  const int q = lane >> 4, mr = lane & 15;

  #pragma unroll 1
  for (int kt = 0; kt < 32; ++kt) {
    const int ko = kt * 32;
    gl2lds16(ga + ko, la);
    gl2lds16(ga + (long)64 * KDIM + ko, la + 2048);
    gl2lds16(gb + ko, lb);
    gl2lds16(gb + (long)64 * KDIM + ko, lb + 2048);
    __syncthreads();   // compiler drains vmcnt before s_barrier

    bh8 af[4], bfv[4];
    #pragma unroll
    for (int t = 0; t < 4; ++t)
      af[t] = *(const bh8*)&As[(wm * 64 + t * 16 + mr) * 32 + q * 8];
    #pragma unroll
    for (int t = 0; t < 4; ++t)
      bfv[t] = *(const bh8*)&Bs[(wn * 64 + t * 16 + mr) * 32 + q * 8];

    #pragma unroll
    for (int mt = 0; mt < 4; ++mt)
      #pragma unroll
      for (int nt = 0; nt < 4; ++nt)
        acc[mt][nt] = mfma_bf16(af[mt], bfv[nt], acc[mt][nt]);
    __syncthreads();
  }

  // C/D layout: col = lane&15, row = (lane>>4)*4 + reg   [m89 verified]
  #pragma unroll
  for (int mt = 0; mt < 4; ++mt) {
    #pragma unroll
    for (int nt = 0; nt < 4; ++nt) {
      long n = tileN + wn * 64 + nt * 16 + mr;
      #pragma unroll
      for (int i = 0; i < 4; ++i) {
        long m = tileM + wm * 64 + mt * 16 + q * 4 + i;
        if constexpr (BF16OUT) {
          ((unsigned short*)Cout)[m * N + n] = f2bf(acc[mt][nt][i]);
        } else {
          ((float*)Cout)[m * N + n] = acc[mt][nt][i] + bias[n];
        }
      }
    }
  }
}

// Persistent GRU: 64 WGs x 256 threads. WG wg owns dims [16wg,16wg+16) for all
// 3 gates; w_hh B-fragments (3 gates x 8 k-iters) persist in registers.
// K split across 4 waves (256 each), LDS reduction, per-step agent-scope barrier.
#define GRU_WGS 64
__global__ __launch_bounds__(256, 1) void gru_kernel(
    const unsigned short* __restrict__ gi,   // [M_ROWS][3072] bf16 (x @ w_ih^T, no bias)
    const unsigned short* __restrict__ whh,  // [3072][1024] bf16
    const float* __restrict__ b_ih,
    const float* __restrict__ b_hh,
    unsigned short* __restrict__ hbuf,       // [2][16][1024] bf16 ping-pong
    unsigned short* __restrict__ rnn,        // [M_ROWS][1024] bf16
    float* __restrict__ hidden_out,          // [16][1024] fp32 (d_out hidden region)
    unsigned* __restrict__ ctr)              // [SEQ] zeroed
{
  const int wg = blockIdx.x;
  const int tid = threadIdx.x;
  const int wv = tid >> 6, lane = tid & 63;
  const int D0 = wg * 16;
  const int q = lane >> 4, nn = lane & 15;

  // persistent B-frags: B[k=q*8+j][n=nn] from w_hh rows (g*1024 + D0 + nn)
  bh8 wf[3][8];
  #pragma unroll
  for (int g = 0; g < 3; ++g)
    #pragma unroll
    for (int kk = 0; kk < 8; ++kk) {
      int k = wv * 256 + kk * 32 + q * 8;
      wf[g][kk] = *(const bh8*)&whh[(size_t)(g * 1024 + D0 + nn) * 1024 + k];
    }

  // gate-phase mapping: one thread per (batch, dim)
  const int b = tid >> 4, dd = tid & 15, d = D0 + dd;
  const float bir = b_ih[d], biz = b_ih[1024 + d], bin_ = b_ih[2048 + d];
  const float bhr = b_hh[d], bhz = b_hh[1024 + d], bhn = b_hh[2048 + d];
  float hreg = 0.0f;
  const unsigned short* gi_base = gi + (size_t)b * SEQ * 3072 + d;

  __shared__ float red[4][3][16][16];   // 12 KB

  #pragma unroll 1
  for (int s = 0; s < SEQ; ++s) {
    const unsigned short* hsrc = hbuf + (s & 1) * 16384;
    unsigned short* hdst = hbuf + ((s + 1) & 1) * 16384;

    f32x4 acc0 = {0.f,0.f,0.f,0.f}, acc1 = {0.f,0.f,0.f,0.f}, acc2 = {0.f,0.f,0.f,0.f};
    #pragma unroll
    for (int kk = 0; kk < 8; ++kk) {
      int k = wv * 256 + kk * 32 + q * 8;
      bh8 af = *(const bh8*)&hsrc[nn * 1024 + k];   // A[m=lane&15][k=q*8+j]
      acc0 = mfma_bf16(af, wf[0][kk], acc0);
      acc1 = mfma_bf16(af, wf[1][kk], acc1);
      acc2 = mfma_bf16(af, wf[2][kk], acc2);
    }
    #pragma unroll
    for (int i = 0; i < 4; ++i) {   // C: row=q*4+i (batch), col=nn (dim)
      red[wv][0][q * 4 + i][nn] = acc0[i];
      red[wv][1][q * 4 + i][nn] = acc1[i];
      red[wv][2][q * 4 + i][nn] = acc2[i];
    }
    __syncthreads();

    float ghr = red[0][0][b][dd] + red[1][0][b][dd] + red[2][0][b][dd] + red[3][0][b][dd];
    float ghz = red[0][1][b][dd] + red[1][1][b][dd] + red[2][1][b][dd] + red[3][1][b][dd];
    float ghn = red[0][2][b][dd] + red[1][2][b][dd] + red[2][2][b][dd] + red[3][2][b][dd];

    const unsigned short* gr = gi_base + (size_t)s * 3072;
    float gir = bf2f(gr[0]);
    float giz = bf2f(gr[1024]);
    float gin = bf2f(gr[2048]);

    float xr = gir + bir + ghr + bhr;
    float xz = giz + biz + ghz + bhz;
    float r = 1.0f / (1.0f + __expf(-xr));
    float z = 1.0f / (1.0f + __expf(-xz));
    float u = gin + bin_ + r * (ghn + bhn);
    float e = __expf(-2.0f * fabsf(u));
    float t = (1.0f - e) / (1.0f + e);
    float nv = copysignf(t, u);
    hreg = (1.0f - z) * nv + z * hreg;

    unsigned short hb = f2bf(hreg);
    hdst[b * 1024 + d] = hb;
    rnn[((size_t)b * SEQ + s) * 1024 + d] = hb;
    if (s == SEQ - 1) hidden_out[b * 1024 + d] = hreg;

    __syncthreads();   // drains all waves' stores (vmcnt(0) before s_barrier)
    if (tid == 0) {
      __hip_atomic_fetch_add(&ctr[s], 1u, __ATOMIC_RELEASE, __HIP_MEMORY_SCOPE_AGENT);
      unsigned v;
      do {
        v = __hip_atomic_load(&ctr[s], __ATOMIC_RELAXED, __HIP_MEMORY_SCOPE_AGENT);
      } while (v < (unsigned)GRU_WGS);
      (void)__hip_atomic_load(&ctr[s], __ATOMIC_ACQUIRE, __HIP_MEMORY_SCOPE_AGENT);
    }
    __syncthreads();
  }
}

extern "C" void kernel_launch(void* const* d_in, const int* in_sizes, int n_in,
                              void* d_out, int out_size, void* d_ws, size_t ws_size,
                              hipStream_t stream) {
  const float* x    = (const float*)d_in[0];
  // d_in[1..4] = attn_w1/b1/w2/b2 — dead: softmax over a size-1 axis is identically 1.
  const float* w_ih = (const float*)d_in[5];
  const float* w_hh = (const float*)d_in[6];
  const float* b_ih = (const float*)d_in[7];
  const float* b_hh = (const float*)d_in[8];
  const float* fc_w = (const float*)d_in[9];
  const float* fc_b = (const float*)d_in[10];

  float* out        = (float*)d_out;                       // [16,2048,1024]
  float* hidden_out = out + (size_t)M_ROWS * 1024;         // [1,16,1024]
  float* attn_out   = hidden_out + 16 * 1024;              // [16,2048,1]

  char* ws = (char*)d_ws;
  unsigned short* x_bf   = (unsigned short*)(ws);                 // 67,108,864 B
  unsigned short* wih_bf = (unsigned short*)(ws + 67108864);      //  6,291,456
  unsigned short* whh_bf = (unsigned short*)(ws + 73400320);      //  6,291,456
  unsigned short* fcw_bf = (unsigned short*)(ws + 79691776);      //  2,097,152
  unsigned short* gi_bf  = (unsigned short*)(ws + 81788928);      // 201,326,592
  unsigned short* rnn_bf = (unsigned short*)(ws + 283115520);     // 67,108,864
  unsigned short* hbuf   = (unsigned short*)(ws + 350224384);     //     65,536
  unsigned*       ctr    = (unsigned*)(ws + 350289920);           //      8,192
  // total ws use: 350,298,112 B

  hipMemsetAsync(hbuf, 0, 65536 + 8192, stream);   // h0 = 0, barrier counters = 0

  cvt_bf16_kernel<<<32768, 256, 0, stream>>>(x, x_bf, 8388608);
  cvt_bf16_kernel<<<3072, 256, 0, stream>>>(w_ih, wih_bf, 786432);
  cvt_bf16_kernel<<<3072, 256, 0, stream>>>(w_hh, whh_bf, 786432);
  cvt_bf16_kernel<<<1024, 256, 0, stream>>>(fc_w, fcw_bf, 262144);
  fill_ones_kernel<<<128, 256, 0, stream>>>(attn_out, 32768);

  // gi = x @ w_ih^T  (bias deferred into gate math), bf16 out
  gemm_nt<true><<<dim3(24, 256), 256, 0, stream>>>(x_bf, wih_bf, gi_bf, nullptr, 3072);

  gru_kernel<<<GRU_WGS, 256, 0, stream>>>(gi_bf, whh_bf, b_ih, b_hh, hbuf, rnn_bf,
                                          hidden_out, ctr);

  // output = rnn @ fc_w^T + fc_b, fp32 out
  gemm_nt<false><<<dim3(8, 256), 256, 0, stream>>>(rnn_bf, fcw_bf, out, fc_b, 1024);
}